// Round 4
// baseline (5649.031 us; speedup 1.0000x reference)
//
#include <hip/hip_runtime.h>
#include <hip/hip_bf16.h>

namespace {

constexpr int T = 100;   // seq len
constexpr int H = 32;    // GRU hidden
constexpr int G = 96;    // 3*H (gates r|z|n)
constexpr int M = 64;    // MLP hidden
constexpr int NSCAL = 4;
constexpr int NIN = NSCAL + H;  // 36

__device__ __forceinline__ float fast_exp(float x) {
  // e^x = 2^(x*log2e); v_exp_f32 saturates to +inf / 0 cleanly.
  return __builtin_amdgcn_exp2f(x * 1.4426950408889634f);
}
__device__ __forceinline__ float fast_rcp(float x) {
  return __builtin_amdgcn_rcpf(x);
}
__device__ __forceinline__ float fast_sigmoid(float x) {
  // x -> -inf: exp -> +inf, rcp -> 0.  x -> +inf: exp -> 0, rcp(1) = 1.
  return fast_rcp(1.0f + fast_exp(-x));
}
__device__ __forceinline__ float fast_tanh(float x) {
  // tanh(x) = 1 - 2/(e^{2x}+1); saturates to +/-1 without NaN.
  float p = fast_exp(2.0f * x);
  return fmaf(-2.0f, fast_rcp(p + 1.0f), 1.0f);
}

__global__ __launch_bounds__(256) void lrpred_kernel(
    const float* __restrict__ loss_history,   // [B, T]
    const float* __restrict__ weight_norm,    // [B]
    const float* __restrict__ grad_norm,      // [B]
    const float* __restrict__ loss_current,   // [B]
    const float* __restrict__ step_progress,  // [B]
    const float* __restrict__ Wi,             // [3H]
    const float* __restrict__ Wh,             // [H, 3H]
    const float* __restrict__ bh,             // [3H]
    const float* __restrict__ W1,             // [36, 64]
    const float* __restrict__ b1,             // [64]
    const float* __restrict__ W2,             // [64, 64]
    const float* __restrict__ b2,             // [64]
    const float* __restrict__ W3,             // [64, 1]
    const float* __restrict__ b3,             // [1]
    float* __restrict__ out,                  // [B]
    int B)
{
  const int b = blockIdx.x * blockDim.x + threadIdx.x;
  if (b >= B) return;

  const float* __restrict__ row = loss_history + (size_t)b * T;

  float h[H];
#pragma unroll
  for (int k = 0; k < H; ++k) h[k] = 0.0f;

  for (int t = 0; t < T; ++t) {
    const float x = row[t];

    // gh = h @ Wh + bh   (acc[j], j in [0,96))
    float acc[G];
#pragma unroll
    for (int j = 0; j < G; ++j) acc[j] = bh[j];
#pragma unroll
    for (int k = 0; k < H; ++k) {
      const float hk = h[k];
#pragma unroll
      for (int j = 0; j < G; ++j)
        acc[j] = fmaf(hk, Wh[k * G + j], acc[j]);
    }

    // gates: r = sig(x*Wi_r + gh_r), z = sig(x*Wi_z + gh_z),
    //        n = tanh(x*Wi_n + r*gh_n), h = (1-z)*n + z*h
#pragma unroll
    for (int j = 0; j < H; ++j) {
      const float r = fast_sigmoid(fmaf(x, Wi[j], acc[j]));
      const float z = fast_sigmoid(fmaf(x, Wi[H + j], acc[H + j]));
      const float n = fast_tanh(fmaf(x, Wi[2 * H + j], r * acc[2 * H + j]));
      h[j] = fmaf(z, h[j] - n, n);   // n + z*(h-n)
    }
  }

  // MLP head: x = [scal(4) | h(32)]
  float xin[NIN];
  xin[0] = weight_norm[b];
  xin[1] = grad_norm[b];
  xin[2] = loss_current[b];
  xin[3] = step_progress[b];
#pragma unroll
  for (int k = 0; k < H; ++k) xin[NSCAL + k] = h[k];

  float a1[M];
#pragma unroll
  for (int m = 0; m < M; ++m) a1[m] = b1[m];
#pragma unroll
  for (int i = 0; i < NIN; ++i) {
    const float xi = xin[i];
#pragma unroll
    for (int m = 0; m < M; ++m)
      a1[m] = fmaf(xi, W1[i * M + m], a1[m]);
  }
#pragma unroll
  for (int m = 0; m < M; ++m) a1[m] = fmaxf(a1[m], 0.0f);

  float a2[M];
#pragma unroll
  for (int m = 0; m < M; ++m) a2[m] = b2[m];
#pragma unroll
  for (int i = 0; i < M; ++i) {
    const float xi = a1[i];
#pragma unroll
    for (int m = 0; m < M; ++m)
      a2[m] = fmaf(xi, W2[i * M + m], a2[m]);
  }
#pragma unroll
  for (int m = 0; m < M; ++m) a2[m] = fmaxf(a2[m], 0.0f);

  float logit = b3[0];
#pragma unroll
  for (int m = 0; m < M; ++m) logit = fmaf(a2[m], W3[m], logit);

  // sigmoid(logit) * (LR_MAX - LR_MIN) + LR_MIN
  out[b] = fmaf(fast_sigmoid(logit), 100.0f - 1e-8f, 1e-8f);
}

}  // namespace

extern "C" void kernel_launch(void* const* d_in, const int* in_sizes, int n_in,
                              void* d_out, int out_size, void* d_ws, size_t ws_size,
                              hipStream_t stream) {
  const float* loss_history  = (const float*)d_in[0];
  const float* weight_norm   = (const float*)d_in[1];
  const float* grad_norm     = (const float*)d_in[2];
  const float* loss_current  = (const float*)d_in[3];
  const float* step_progress = (const float*)d_in[4];
  const float* Wi            = (const float*)d_in[5];
  const float* Wh            = (const float*)d_in[6];
  const float* bh            = (const float*)d_in[7];
  const float* W1            = (const float*)d_in[8];
  const float* b1            = (const float*)d_in[9];
  const float* W2            = (const float*)d_in[10];
  const float* b2            = (const float*)d_in[11];
  const float* W3            = (const float*)d_in[12];
  const float* b3            = (const float*)d_in[13];
  float* out = (float*)d_out;

  const int B = in_sizes[1];  // weight_norm is [B]
  const int grid = (B + 255) / 256;
  lrpred_kernel<<<grid, 256, 0, stream>>>(
      loss_history, weight_norm, grad_norm, loss_current, step_progress,
      Wi, Wh, bh, W1, b1, W2, b2, W3, b3, out, B);
}

// Round 5
// 5243.783 us; speedup vs baseline: 1.0773x; 1.0773x over previous
//
#include <hip/hip_runtime.h>

namespace {

constexpr int T = 100;   // seq len
constexpr int H = 32;    // GRU hidden
constexpr int M = 64;    // MLP hidden

__device__ __forceinline__ float fast_exp(float x) {
  return __builtin_amdgcn_exp2f(x * 1.4426950408889634f);
}
__device__ __forceinline__ float fast_rcp(float x) {
  return __builtin_amdgcn_rcpf(x);
}
__device__ __forceinline__ float fast_sigmoid(float x) {
  return fast_rcp(1.0f + fast_exp(-x));
}
__device__ __forceinline__ float fast_tanh(float x) {
  float p = fast_exp(2.0f * x);
  return fmaf(-2.0f, fast_rcp(p + 1.0f), 1.0f);
}

// Phase-split GRU step keeps peak live registers ~110 (h[32] + one 32-wide
// accumulator + carried n[32]) so nothing spills to AGPRs. R4 baseline
// (acc[96] all at once) allocated 132 arch VGPRs + AGPR shuttle -> 1
// wave/SIMD occupancy and ~4x VALU bloat.
__global__ __launch_bounds__(256) void lrpred_kernel(
    const float* __restrict__ loss_history,   // [B, T]
    const float* __restrict__ weight_norm,    // [B]
    const float* __restrict__ grad_norm,      // [B]
    const float* __restrict__ loss_current,   // [B]
    const float* __restrict__ step_progress,  // [B]
    const float* __restrict__ Wi,             // [3H]
    const float* __restrict__ Wh,             // [H, 3H]
    const float* __restrict__ bh,             // [3H]
    const float* __restrict__ W1,             // [36, 64]
    const float* __restrict__ b1,             // [64]
    const float* __restrict__ W2,             // [64, 64]
    const float* __restrict__ b2,             // [64]
    const float* __restrict__ W3,             // [64, 1]
    const float* __restrict__ b3,             // [1]
    float* __restrict__ out,                  // [B]
    int B)
{
  const int b = blockIdx.x * blockDim.x + threadIdx.x;
  if (b >= B) return;

  const float* __restrict__ row = loss_history + (size_t)b * T;

  float h[H];
#pragma unroll
  for (int k = 0; k < H; ++k) h[k] = 0.0f;

  float xn = row[0];
  for (int t = 0; t < T; ++t) {
    const float x = xn;
    if (t + 1 < T) xn = row[t + 1];   // prefetch next step's input

    // ---- phase N: gn = bh_n + h @ Wh_n  (cols 64..95) ----
    float gn[H];
#pragma unroll
    for (int j = 0; j < H; ++j) gn[j] = bh[2 * H + j];
#pragma unroll
    for (int k = 0; k < H; ++k) {
      const float hk = h[k];
#pragma unroll
      for (int j = 0; j < H; ++j)
        gn[j] = fmaf(hk, Wh[k * 3 * H + 2 * H + j], gn[j]);
    }

    // ---- phase R: ar = bh_r + h @ Wh_r; fold r into n in place ----
    {
      float ar[H];
#pragma unroll
      for (int j = 0; j < H; ++j) ar[j] = bh[j];
#pragma unroll
      for (int k = 0; k < H; ++k) {
        const float hk = h[k];
#pragma unroll
        for (int j = 0; j < H; ++j)
          ar[j] = fmaf(hk, Wh[k * 3 * H + j], ar[j]);
      }
#pragma unroll
      for (int j = 0; j < H; ++j) {
        const float r = fast_sigmoid(fmaf(x, Wi[j], ar[j]));
        gn[j] = fast_tanh(fmaf(x, Wi[2 * H + j], r * gn[j]));  // gn <- n
      }
    }

    // ---- phase Z: az = bh_z + h @ Wh_z; fold z + update h ----
    {
      float az[H];
#pragma unroll
      for (int j = 0; j < H; ++j) az[j] = bh[H + j];
#pragma unroll
      for (int k = 0; k < H; ++k) {
        const float hk = h[k];
#pragma unroll
        for (int j = 0; j < H; ++j)
          az[j] = fmaf(hk, Wh[k * 3 * H + H + j], az[j]);
      }
#pragma unroll
      for (int j = 0; j < H; ++j) {
        const float z = fast_sigmoid(fmaf(x, Wi[H + j], az[j]));
        h[j] = fmaf(z, h[j] - gn[j], gn[j]);   // n + z*(h-n)
      }
    }
  }

  // ---- MLP head, phase-split so the epilogue doesn't set the VGPR peak ----
  const float s0 = weight_norm[b];
  const float s1 = grad_norm[b];
  const float s2 = loss_current[b];
  const float s3 = step_progress[b];

  float a1[M];
#pragma unroll
  for (int m = 0; m < M; ++m) a1[m] = b1[m];
#pragma unroll
  for (int m = 0; m < M; ++m) a1[m] = fmaf(s0, W1[0 * M + m], a1[m]);
#pragma unroll
  for (int m = 0; m < M; ++m) a1[m] = fmaf(s1, W1[1 * M + m], a1[m]);
#pragma unroll
  for (int m = 0; m < M; ++m) a1[m] = fmaf(s2, W1[2 * M + m], a1[m]);
#pragma unroll
  for (int m = 0; m < M; ++m) a1[m] = fmaf(s3, W1[3 * M + m], a1[m]);
#pragma unroll
  for (int k = 0; k < H; ++k) {
    const float hk = h[k];
#pragma unroll
    for (int m = 0; m < M; ++m)
      a1[m] = fmaf(hk, W1[(4 + k) * M + m], a1[m]);
  }
#pragma unroll
  for (int m = 0; m < M; ++m) a1[m] = fmaxf(a1[m], 0.0f);

  float logit = b3[0];
#pragma unroll
  for (int hf = 0; hf < 2; ++hf) {          // a2 in 32-wide halves
    float a2[32];
#pragma unroll
    for (int m = 0; m < 32; ++m) a2[m] = b2[hf * 32 + m];
#pragma unroll
    for (int i = 0; i < M; ++i) {
      const float xi = a1[i];
#pragma unroll
      for (int m = 0; m < 32; ++m)
        a2[m] = fmaf(xi, W2[i * M + hf * 32 + m], a2[m]);
    }
#pragma unroll
    for (int m = 0; m < 32; ++m)
      logit = fmaf(fmaxf(a2[m], 0.0f), W3[hf * 32 + m], logit);
  }

  out[b] = fmaf(fast_sigmoid(logit), 100.0f - 1e-8f, 1e-8f);
}

}  // namespace

extern "C" void kernel_launch(void* const* d_in, const int* in_sizes, int n_in,
                              void* d_out, int out_size, void* d_ws, size_t ws_size,
                              hipStream_t stream) {
  const float* loss_history  = (const float*)d_in[0];
  const float* weight_norm   = (const float*)d_in[1];
  const float* grad_norm     = (const float*)d_in[2];
  const float* loss_current  = (const float*)d_in[3];
  const float* step_progress = (const float*)d_in[4];
  const float* Wi            = (const float*)d_in[5];
  const float* Wh            = (const float*)d_in[6];
  const float* bh            = (const float*)d_in[7];
  const float* W1            = (const float*)d_in[8];
  const float* b1            = (const float*)d_in[9];
  const float* W2            = (const float*)d_in[10];
  const float* b2            = (const float*)d_in[11];
  const float* W3            = (const float*)d_in[12];
  const float* b3            = (const float*)d_in[13];
  float* out = (float*)d_out;

  const int B = in_sizes[1];  // weight_norm is [B]
  const int grid = (B + 255) / 256;
  lrpred_kernel<<<grid, 256, 0, stream>>>(
      loss_history, weight_norm, grad_norm, loss_current, step_progress,
      Wi, Wh, bh, W1, b1, W2, b2, W3, b3, out, B);
}

// Round 7
// 964.203 us; speedup vs baseline: 5.8588x; 5.4385x over previous
//
#include <hip/hip_runtime.h>

namespace {

typedef __attribute__((ext_vector_type(8))) short short8;   // 8 bf16 = 4 VGPRs (MFMA A/B frag)
typedef __attribute__((ext_vector_type(4))) float floatx4;  // MFMA C/D frag

constexpr int T = 100;   // seq len
constexpr int H = 32;    // GRU hidden
constexpr int M = 64;    // MLP hidden
constexpr float L2E = 1.4426950408889634f;

__device__ __forceinline__ float fast_exp2(float x) { return __builtin_amdgcn_exp2f(x); }
__device__ __forceinline__ float fast_rcp(float x)  { return __builtin_amdgcn_rcpf(x); }
__device__ __forceinline__ float fast_sigmoid(float x) {  // plain, for final logit
  return fast_rcp(1.0f + fast_exp2(-L2E * x));
}

__device__ __forceinline__ unsigned short bf16_rne(float f) {
  unsigned u = __float_as_uint(f);
  return (unsigned short)((u + 0x7FFFu + ((u >> 16) & 1u)) >> 16);
}
__device__ __forceinline__ float bf16_f32(unsigned short s) {
  return __uint_as_float(((unsigned)s) << 16);
}

// One wave = 64 batch rows. gh^T = Wh^T @ h^T via mfma_f32_16x16x32_bf16.
// A (Wh^T) preloaded once as hi/lo bf16 frags (split-bf16, 3 passes ~ fp32).
// C-layout (m89): col=lane&15 (batch), row=(lane>>4)*4+reg (gate) -- the
// per-lane j-quads {4p..4p+3}u{16+4p..19+4p} equal the B-frag k-set, so h
// state stays in registers across steps: NO LDS in the recurrent loop.
// NOTE: correctness is invariant to the true A/B k-mapping as long as A and
// B use the same convention (k-permutation cancels in the dot product).
__global__ __launch_bounds__(256, 2) void lrpred_kernel(
    const float* __restrict__ loss_history,   // [B, T]
    const float* __restrict__ weight_norm,    // [B]
    const float* __restrict__ grad_norm,      // [B]
    const float* __restrict__ loss_current,   // [B]
    const float* __restrict__ step_progress,  // [B]
    const float* __restrict__ Wi,             // [3H]
    const float* __restrict__ Wh,             // [H, 3H]
    const float* __restrict__ bh,             // [3H]
    const float* __restrict__ W1,             // [36, 64]
    const float* __restrict__ b1,             // [64]
    const float* __restrict__ W2,             // [64, 64]
    const float* __restrict__ b2,             // [64]
    const float* __restrict__ W3,             // [64, 1]
    const float* __restrict__ b3,             // [1]
    float* __restrict__ out,                  // [B]
    int B)                                    // B % 256 == 0 (grid exact)
{
  const int lane = threadIdx.x & 63;
  const int wid  = threadIdx.x >> 6;
  const int c = lane & 15;   // tile column (batch within 16-group / gate col g%16)
  const int p = lane >> 4;   // quad selector
  const int blockBase = blockIdx.x * 256;
  const int waveBase  = blockBase + wid * 64;

  // ---- one-time: A-frags = Wh^T, pre-scaled, split hi/lo bf16 ----
  // A[g][k] layout: lane holds row g = mt*16 + c, k in {4p..4p+3, 16+4p..19+4p}
  // r,z tiles (mt 0..3) scaled by -log2e (sigmoid); n tiles (mt 4,5) by +2log2e (tanh).
  short8 wHi[6], wLo[6];
#pragma unroll
  for (int mt = 0; mt < 6; ++mt) {
    const float sc = (mt < 4) ? -L2E : (2.0f * L2E);
    short8 hi, lo;
#pragma unroll
    for (int e = 0; e < 8; ++e) {
      const int k = (e >> 2) * 16 + 4 * p + (e & 3);
      const float w = Wh[k * (3 * H) + mt * 16 + c] * sc;
      const unsigned short h16 = bf16_rne(w);
      hi[e] = (short)h16;
      lo[e] = (short)bf16_rne(w - bf16_f32(h16));
    }
    wHi[mt] = hi;
    wLo[mt] = lo;
  }

  // ---- one-time: per-lane Wi / bh (same scaling folded in) ----
  float wiR[8], wiZ[8], wiN[8], bhR[8], bhZ[8], bhN[8];
#pragma unroll
  for (int e = 0; e < 8; ++e) {
    const int j = (e >> 2) * 16 + 4 * p + (e & 3);
    wiR[e] = Wi[j]          * -L2E;          bhR[e] = bh[j]          * -L2E;
    wiZ[e] = Wi[H + j]      * -L2E;          bhZ[e] = bh[H + j]      * -L2E;
    wiN[e] = Wi[2 * H + j]  * (2.0f * L2E);  bhN[e] = bh[2 * H + j]  * (2.0f * L2E);
  }

  // ---- h state in registers: hs[nt][e] = h[batch nt*16+c][j=(e>>2)*16+4p+(e&3)] ----
  float hs[4][8];
#pragma unroll
  for (int nt = 0; nt < 4; ++nt)
#pragma unroll
    for (int e = 0; e < 8; ++e) hs[nt][e] = 0.0f;

  // x pointers: lane reads x for its 4 batch columns (one per nt)
  const float* xp0 = loss_history + (size_t)(waveBase +  0 + c) * T;
  const float* xp1 = loss_history + (size_t)(waveBase + 16 + c) * T;
  const float* xp2 = loss_history + (size_t)(waveBase + 32 + c) * T;
  const float* xp3 = loss_history + (size_t)(waveBase + 48 + c) * T;
  float xv[4], xn[4];
  xv[0] = xp0[0]; xv[1] = xp1[0]; xv[2] = xp2[0]; xv[3] = xp3[0];

#pragma unroll 1
  for (int t = 0; t < T; ++t) {
    if (t + 1 < T) {  // prefetch next step's inputs (uniform branch)
      xn[0] = xp0[t + 1]; xn[1] = xp1[t + 1]; xn[2] = xp2[t + 1]; xn[3] = xp3[t + 1];
    }
#pragma unroll
    for (int nt = 0; nt < 4; ++nt) {
      // B-frag (h^T) build: hi/lo bf16, k-set identical to hs j-set
      short8 bHi, bLo;
#pragma unroll
      for (int e = 0; e < 8; ++e) {
        const float v = hs[nt][e];
        const unsigned short h16 = bf16_rne(v);
        bHi[e] = (short)h16;
        bLo[e] = (short)bf16_rne(v - bf16_f32(h16));
      }
      // acc init = (scaled) bias; MFMA accumulates gh on top
      floatx4 aR0 = {bhR[0], bhR[1], bhR[2], bhR[3]};
      floatx4 aR1 = {bhR[4], bhR[5], bhR[6], bhR[7]};
      floatx4 aZ0 = {bhZ[0], bhZ[1], bhZ[2], bhZ[3]};
      floatx4 aZ1 = {bhZ[4], bhZ[5], bhZ[6], bhZ[7]};
      floatx4 aN0 = {bhN[0], bhN[1], bhN[2], bhN[3]};
      floatx4 aN1 = {bhN[4], bhN[5], bhN[6], bhN[7]};
      // split-bf16: Ahi*Bhi + Alo*Bhi + Ahi*Blo  (drop lo*lo, ~2^-18)
      aR0 = __builtin_amdgcn_mfma_f32_16x16x32_bf16(wHi[0], bHi, aR0, 0, 0, 0);
      aR0 = __builtin_amdgcn_mfma_f32_16x16x32_bf16(wLo[0], bHi, aR0, 0, 0, 0);
      aR0 = __builtin_amdgcn_mfma_f32_16x16x32_bf16(wHi[0], bLo, aR0, 0, 0, 0);
      aR1 = __builtin_amdgcn_mfma_f32_16x16x32_bf16(wHi[1], bHi, aR1, 0, 0, 0);
      aR1 = __builtin_amdgcn_mfma_f32_16x16x32_bf16(wLo[1], bHi, aR1, 0, 0, 0);
      aR1 = __builtin_amdgcn_mfma_f32_16x16x32_bf16(wHi[1], bLo, aR1, 0, 0, 0);
      aZ0 = __builtin_amdgcn_mfma_f32_16x16x32_bf16(wHi[2], bHi, aZ0, 0, 0, 0);
      aZ0 = __builtin_amdgcn_mfma_f32_16x16x32_bf16(wLo[2], bHi, aZ0, 0, 0, 0);
      aZ0 = __builtin_amdgcn_mfma_f32_16x16x32_bf16(wHi[2], bLo, aZ0, 0, 0, 0);
      aZ1 = __builtin_amdgcn_mfma_f32_16x16x32_bf16(wHi[3], bHi, aZ1, 0, 0, 0);
      aZ1 = __builtin_amdgcn_mfma_f32_16x16x32_bf16(wLo[3], bHi, aZ1, 0, 0, 0);
      aZ1 = __builtin_amdgcn_mfma_f32_16x16x32_bf16(wHi[3], bLo, aZ1, 0, 0, 0);
      aN0 = __builtin_amdgcn_mfma_f32_16x16x32_bf16(wHi[4], bHi, aN0, 0, 0, 0);
      aN0 = __builtin_amdgcn_mfma_f32_16x16x32_bf16(wLo[4], bHi, aN0, 0, 0, 0);
      aN0 = __builtin_amdgcn_mfma_f32_16x16x32_bf16(wHi[4], bLo, aN0, 0, 0, 0);
      aN1 = __builtin_amdgcn_mfma_f32_16x16x32_bf16(wHi[5], bHi, aN1, 0, 0, 0);
      aN1 = __builtin_amdgcn_mfma_f32_16x16x32_bf16(wLo[5], bHi, aN1, 0, 0, 0);
      aN1 = __builtin_amdgcn_mfma_f32_16x16x32_bf16(wHi[5], bLo, aN1, 0, 0, 0);

      // gates (all pre-activations arrive pre-scaled; no per-gate mul needed)
      const float xb = xv[nt];
#pragma unroll
      for (int e = 0; e < 8; ++e) {
        const float ar = (e < 4) ? aR0[e & 3] : aR1[e & 3];
        const float az = (e < 4) ? aZ0[e & 3] : aZ1[e & 3];
        const float an = (e < 4) ? aN0[e & 3] : aN1[e & 3];
        const float r  = fast_rcp(1.0f + fast_exp2(fmaf(xb, wiR[e], ar)));
        const float z  = fast_rcp(1.0f + fast_exp2(fmaf(xb, wiZ[e], az)));
        const float pn = fmaf(r, an, xb * wiN[e]);           // scaled by 2log2e
        const float n  = fmaf(-2.0f, fast_rcp(fast_exp2(pn) + 1.0f), 1.0f);
        hs[nt][e] = fmaf(z, hs[nt][e] - n, n);               // n + z*(h-n)
      }
    }
    xv[0] = xn[0]; xv[1] = xn[1]; xv[2] = xn[2]; xv[3] = xn[3];
  }

  // ---- transpose h to per-thread rows via LDS (one-time) ----
  __shared__ float hsh[256][36];   // stride 36 f32 = 144 B (16B-aligned rows)
#pragma unroll
  for (int nt = 0; nt < 4; ++nt) {
    const int row = wid * 64 + nt * 16 + c;
#pragma unroll
    for (int q = 0; q < 2; ++q) {
      floatx4 v = {hs[nt][q * 4 + 0], hs[nt][q * 4 + 1],
                   hs[nt][q * 4 + 2], hs[nt][q * 4 + 3]};
      *(floatx4*)&hsh[row][q * 16 + 4 * p] = v;
    }
  }
  __syncthreads();

  // ---- per-thread fp32 MLP head (phase-split, low VGPR) ----
  const int b = blockBase + threadIdx.x;
  const float s0 = weight_norm[b];
  const float s1 = grad_norm[b];
  const float s2 = loss_current[b];
  const float s3 = step_progress[b];

  float a1[M];
#pragma unroll
  for (int m = 0; m < M; ++m) a1[m] = b1[m];
#pragma unroll
  for (int m = 0; m < M; ++m) a1[m] = fmaf(s0, W1[0 * M + m], a1[m]);
#pragma unroll
  for (int m = 0; m < M; ++m) a1[m] = fmaf(s1, W1[1 * M + m], a1[m]);
#pragma unroll
  for (int m = 0; m < M; ++m) a1[m] = fmaf(s2, W1[2 * M + m], a1[m]);
#pragma unroll
  for (int m = 0; m < M; ++m) a1[m] = fmaf(s3, W1[3 * M + m], a1[m]);
#pragma unroll
  for (int k = 0; k < H; ++k) {
    const float hk = hsh[threadIdx.x][k];
#pragma unroll
    for (int m = 0; m < M; ++m)
      a1[m] = fmaf(hk, W1[(4 + k) * M + m], a1[m]);
  }
#pragma unroll
  for (int m = 0; m < M; ++m) a1[m] = fmaxf(a1[m], 0.0f);

  float logit = b3[0];
#pragma unroll
  for (int hf = 0; hf < 2; ++hf) {
    float a2[32];
#pragma unroll
    for (int m = 0; m < 32; ++m) a2[m] = b2[hf * 32 + m];
#pragma unroll
    for (int i = 0; i < M; ++i) {
      const float xi = a1[i];
#pragma unroll
      for (int m = 0; m < 32; ++m)
        a2[m] = fmaf(xi, W2[i * M + hf * 32 + m], a2[m]);
    }
#pragma unroll
    for (int m = 0; m < 32; ++m)
      logit = fmaf(fmaxf(a2[m], 0.0f), W3[hf * 32 + m], logit);
  }

  out[b] = fmaf(fast_sigmoid(logit), 100.0f - 1e-8f, 1e-8f);
}

}  // namespace

extern "C" void kernel_launch(void* const* d_in, const int* in_sizes, int n_in,
                              void* d_out, int out_size, void* d_ws, size_t ws_size,
                              hipStream_t stream) {
  const float* loss_history  = (const float*)d_in[0];
  const float* weight_norm   = (const float*)d_in[1];
  const float* grad_norm     = (const float*)d_in[2];
  const float* loss_current  = (const float*)d_in[3];
  const float* step_progress = (const float*)d_in[4];
  const float* Wi            = (const float*)d_in[5];
  const float* Wh            = (const float*)d_in[6];
  const float* bh            = (const float*)d_in[7];
  const float* W1            = (const float*)d_in[8];
  const float* b1            = (const float*)d_in[9];
  const float* W2            = (const float*)d_in[10];
  const float* b2            = (const float*)d_in[11];
  const float* W3            = (const float*)d_in[12];
  const float* b3            = (const float*)d_in[13];
  float* out = (float*)d_out;

  const int B = in_sizes[1];          // weight_norm is [B]; B % 256 == 0
  const int grid = B / 256;           // 1 block = 4 waves = 256 batch rows
  lrpred_kernel<<<grid, 256, 0, stream>>>(
      loss_history, weight_norm, grad_norm, loss_current, step_progress,
      Wi, Wh, bh, W1, b1, W2, b2, W3, b3, out, B);
}

// Round 9
// 931.530 us; speedup vs baseline: 6.0643x; 1.0351x over previous
//
#include <hip/hip_runtime.h>

namespace {

typedef __attribute__((ext_vector_type(8))) short short8;   // 8 bf16 = 4 VGPRs (MFMA A/B frag)
typedef __attribute__((ext_vector_type(4))) float floatx4;  // MFMA C/D frag
typedef __attribute__((ext_vector_type(4))) unsigned uint4v;

constexpr int T = 100;   // seq len
constexpr int H = 32;    // GRU hidden
constexpr int M = 64;    // MLP hidden
constexpr float L2E = 1.4426950408889634f;

__device__ __forceinline__ float fast_exp2(float x) { return __builtin_amdgcn_exp2f(x); }
__device__ __forceinline__ float fast_rcp(float x)  { return __builtin_amdgcn_rcpf(x); }
__device__ __forceinline__ float fast_sigmoid(float x) {
  return fast_rcp(1.0f + fast_exp2(-L2E * x));
}

__device__ __forceinline__ unsigned short bf16_rne(float f) {  // one-time setup only
  unsigned u = __float_as_uint(f);
  return (unsigned short)((u + 0x7FFFu + ((u >> 16) & 1u)) >> 16);
}
__device__ __forceinline__ float bf16_f32(unsigned short s) {
  return __uint_as_float(((unsigned)s) << 16);
}
// packed RNE f32->bf16x2: low16=bf16(a), high16=bf16(b)  (hot loop)
__device__ __forceinline__ unsigned cvt_pk_bf16(float a, float b) {
  unsigned r;
  asm("v_cvt_pk_bf16_f32 %0, %1, %2" : "=v"(r) : "v"(a), "v"(b));
  return r;
}

// One wave = 64 batch rows. gh^T = Wh^T @ h^T via mfma_f32_16x16x32_bf16.
// Per acc: 4 MFMA passes: aux (x*Wi + bias, split-bf16) then Ahi*Blo,
// Alo*Bhi, Ahi*Bhi on h. C-layout rows {4p+i, 16+4p+i} equal the B-frag
// k-set, so h stays in registers across steps (no LDS in recurrent loop).
// Correctness invariant to true HW k-permutation: A and B share one e->k map.
__global__ __launch_bounds__(256, 3) void lrpred_kernel(
    const float* __restrict__ loss_history,   // [B, T]
    const float* __restrict__ weight_norm,    // [B]
    const float* __restrict__ grad_norm,      // [B]
    const float* __restrict__ loss_current,   // [B]
    const float* __restrict__ step_progress,  // [B]
    const float* __restrict__ Wi,             // [3H]
    const float* __restrict__ Wh,             // [H, 3H]
    const float* __restrict__ bh,             // [3H]
    const float* __restrict__ W1,             // [36, 64]
    const float* __restrict__ b1,             // [64]
    const float* __restrict__ W2,             // [64, 64]
    const float* __restrict__ b2,             // [64]
    const float* __restrict__ W3,             // [64, 1]
    const float* __restrict__ b3,             // [1]
    float* __restrict__ out,                  // [B]
    int B)                                    // B % 256 == 0 (grid exact)
{
  const int lane = threadIdx.x & 63;
  const int wid  = threadIdx.x >> 6;
  const int c = lane & 15;   // tile column
  const int p = lane >> 4;   // quad selector
  const bool isp0 = (p == 0);
  const int blockBase = blockIdx.x * 256;
  const int waveBase  = blockBase + wid * 64;

  // ---- one-time: A-frags = Wh^T, pre-scaled, split hi/lo bf16 ----
  // lane holds row g = mt*16 + c, k(e) = (e>>2)*16 + 4p + (e&3)
  // r,z tiles (mt 0..3) scaled -log2e; n tiles (mt 4,5) scaled +2log2e.
  short8 wHi[6], wLo[6];
#pragma unroll
  for (int mt = 0; mt < 6; ++mt) {
    const float sc = (mt < 4) ? -L2E : (2.0f * L2E);
    short8 hi, lo;
#pragma unroll
    for (int e = 0; e < 8; ++e) {
      const int k = (e >> 2) * 16 + 4 * p + (e & 3);
      const float w = Wh[k * (3 * H) + mt * 16 + c] * sc;
      const unsigned short h16 = bf16_rne(w);
      hi[e] = (short)h16;
      lo[e] = (short)bf16_rne(w - bf16_f32(h16));
    }
    wHi[mt] = hi;
    wLo[mt] = lo;
  }

  // ---- one-time: aux A-tiles (x*Wi for r,z + biases, split hi/lo) ----
  // k-slots: 0:Wi_hi(*x_hi) 1:Wi_hi(*x_lo) 2:bh_hi(*1) 3:Wi_lo(*x_hi) 4:bh_lo(*1)
  short8 wAux[6];
#pragma unroll
  for (int mt = 0; mt < 6; ++mt) {
    const float sc = (mt < 4) ? -L2E : (2.0f * L2E);
    const int g = mt * 16 + c;
    const float wi_s = (mt < 4) ? Wi[g] * sc : 0.0f;
    const float bh_s = bh[g] * sc;
    const unsigned short wi_hi = bf16_rne(wi_s);
    const unsigned short wi_lo = bf16_rne(wi_s - bf16_f32(wi_hi));
    const unsigned short bh_hi = bf16_rne(bh_s);
    const unsigned short bh_lo = bf16_rne(bh_s - bf16_f32(bh_hi));
    short8 a = {0, 0, 0, 0, 0, 0, 0, 0};
    if (p == 0) {
      a[0] = (short)wi_hi; a[1] = (short)wi_hi;
      a[2] = (short)bh_hi; a[3] = (short)wi_lo;
    } else if (p == 1) {
      a[0] = (short)bh_lo;           // k=4
    }
    wAux[mt] = a;
  }

  // n-gate x*Wi_n stays on VALU (outside the r-product): per-lane consts
  float wiN[8];
#pragma unroll
  for (int e = 0; e < 8; ++e) {
    const int j = (e >> 2) * 16 + 4 * p + (e & 3);
    wiN[e] = Wi[2 * H + j] * (2.0f * L2E);
  }

  // loop-invariant pieces of the aux B-frag
  const unsigned w0_rest = (p == 1) ? 0x00003F80u : 0u;  // k=4 slot: 1.0

  // ---- h state: hs[nt][e] = h[batch nt*16+c][j=(e>>2)*16+4p+(e&3)] ----
  float hs[4][8];
#pragma unroll
  for (int nt = 0; nt < 4; ++nt)
#pragma unroll
    for (int e = 0; e < 8; ++e) hs[nt][e] = 0.0f;

  const float* xp0 = loss_history + (size_t)(waveBase +  0 + c) * T;
  const float* xp1 = loss_history + (size_t)(waveBase + 16 + c) * T;
  const float* xp2 = loss_history + (size_t)(waveBase + 32 + c) * T;
  const float* xp3 = loss_history + (size_t)(waveBase + 48 + c) * T;
  float xv[4], xn[4];
  xv[0] = xp0[0]; xv[1] = xp1[0]; xv[2] = xp2[0]; xv[3] = xp3[0];

  const floatx4 z4 = {0.0f, 0.0f, 0.0f, 0.0f};   // shared MFMA C-init

#pragma unroll 1
  for (int t = 0; t < T; ++t) {
    if (t + 1 < T) {
      xn[0] = xp0[t + 1]; xn[1] = xp1[t + 1]; xn[2] = xp2[t + 1]; xn[3] = xp3[t + 1];
    }
#pragma unroll
    for (int nt = 0; nt < 4; ++nt) {
      // --- B h-frag via cvt_pk (hi) + unpack/sub/cvt_pk (lo) ---
      unsigned hw0 = cvt_pk_bf16(hs[nt][0], hs[nt][1]);
      unsigned hw1 = cvt_pk_bf16(hs[nt][2], hs[nt][3]);
      unsigned hw2 = cvt_pk_bf16(hs[nt][4], hs[nt][5]);
      unsigned hw3 = cvt_pk_bf16(hs[nt][6], hs[nt][7]);
      unsigned lw0 = cvt_pk_bf16(hs[nt][0] - __uint_as_float(hw0 << 16),
                                 hs[nt][1] - __uint_as_float(hw0 & 0xFFFF0000u));
      unsigned lw1 = cvt_pk_bf16(hs[nt][2] - __uint_as_float(hw1 << 16),
                                 hs[nt][3] - __uint_as_float(hw1 & 0xFFFF0000u));
      unsigned lw2 = cvt_pk_bf16(hs[nt][4] - __uint_as_float(hw2 << 16),
                                 hs[nt][5] - __uint_as_float(hw2 & 0xFFFF0000u));
      unsigned lw3 = cvt_pk_bf16(hs[nt][6] - __uint_as_float(hw3 << 16),
                                 hs[nt][7] - __uint_as_float(hw3 & 0xFFFF0000u));
      short8 bHi = __builtin_bit_cast(short8, (uint4v){hw0, hw1, hw2, hw3});
      short8 bLo = __builtin_bit_cast(short8, (uint4v){lw0, lw1, lw2, lw3});

      // --- aux B-frag: k0:x_hi k1:x_lo k2:1.0 k3:x_hi (p==0), k4:1.0 (p==1) ---
      const float xb = xv[nt];
      unsigned u0 = cvt_pk_bf16(xb, 0.0f);                   // low16 = x_hi
      float xlo = xb - __uint_as_float(u0 << 16);
      unsigned w0p0 = cvt_pk_bf16(xb, xlo);                  // {x_hi | x_lo}
      unsigned w1p0 = (u0 << 16) | 0x3F80u;                  // {1.0 | x_hi}
      unsigned bw0 = isp0 ? w0p0 : w0_rest;
      unsigned bw1 = isp0 ? w1p0 : 0u;
      short8 bAux = __builtin_bit_cast(short8, (uint4v){bw0, bw1, 0u, 0u});

      // --- 4 passes per acc: aux, Ahi*Blo, Alo*Bhi, Ahi*Bhi ---
      floatx4 aR0 = __builtin_amdgcn_mfma_f32_16x16x32_bf16(wAux[0], bAux, z4, 0, 0, 0);
      floatx4 aR1 = __builtin_amdgcn_mfma_f32_16x16x32_bf16(wAux[1], bAux, z4, 0, 0, 0);
      floatx4 aZ0 = __builtin_amdgcn_mfma_f32_16x16x32_bf16(wAux[2], bAux, z4, 0, 0, 0);
      floatx4 aZ1 = __builtin_amdgcn_mfma_f32_16x16x32_bf16(wAux[3], bAux, z4, 0, 0, 0);
      floatx4 aN0 = __builtin_amdgcn_mfma_f32_16x16x32_bf16(wAux[4], bAux, z4, 0, 0, 0);
      floatx4 aN1 = __builtin_amdgcn_mfma_f32_16x16x32_bf16(wAux[5], bAux, z4, 0, 0, 0);
      aR0 = __builtin_amdgcn_mfma_f32_16x16x32_bf16(wHi[0], bLo, aR0, 0, 0, 0);
      aR1 = __builtin_amdgcn_mfma_f32_16x16x32_bf16(wHi[1], bLo, aR1, 0, 0, 0);
      aZ0 = __builtin_amdgcn_mfma_f32_16x16x32_bf16(wHi[2], bLo, aZ0, 0, 0, 0);
      aZ1 = __builtin_amdgcn_mfma_f32_16x16x32_bf16(wHi[3], bLo, aZ1, 0, 0, 0);
      aN0 = __builtin_amdgcn_mfma_f32_16x16x32_bf16(wHi[4], bLo, aN0, 0, 0, 0);
      aN1 = __builtin_amdgcn_mfma_f32_16x16x32_bf16(wHi[5], bLo, aN1, 0, 0, 0);
      aR0 = __builtin_amdgcn_mfma_f32_16x16x32_bf16(wLo[0], bHi, aR0, 0, 0, 0);
      aR1 = __builtin_amdgcn_mfma_f32_16x16x32_bf16(wLo[1], bHi, aR1, 0, 0, 0);
      aZ0 = __builtin_amdgcn_mfma_f32_16x16x32_bf16(wLo[2], bHi, aZ0, 0, 0, 0);
      aZ1 = __builtin_amdgcn_mfma_f32_16x16x32_bf16(wLo[3], bHi, aZ1, 0, 0, 0);
      aN0 = __builtin_amdgcn_mfma_f32_16x16x32_bf16(wLo[4], bHi, aN0, 0, 0, 0);
      aN1 = __builtin_amdgcn_mfma_f32_16x16x32_bf16(wLo[5], bHi, aN1, 0, 0, 0);
      aR0 = __builtin_amdgcn_mfma_f32_16x16x32_bf16(wHi[0], bHi, aR0, 0, 0, 0);
      aR1 = __builtin_amdgcn_mfma_f32_16x16x32_bf16(wHi[1], bHi, aR1, 0, 0, 0);
      aZ0 = __builtin_amdgcn_mfma_f32_16x16x32_bf16(wHi[2], bHi, aZ0, 0, 0, 0);
      aZ1 = __builtin_amdgcn_mfma_f32_16x16x32_bf16(wHi[3], bHi, aZ1, 0, 0, 0);
      aN0 = __builtin_amdgcn_mfma_f32_16x16x32_bf16(wHi[4], bHi, aN0, 0, 0, 0);
      aN1 = __builtin_amdgcn_mfma_f32_16x16x32_bf16(wHi[5], bHi, aN1, 0, 0, 0);

      // --- gates: pre-activations arrive pre-scaled with bias+gi included ---
#pragma unroll
      for (int e = 0; e < 8; ++e) {
        const float ar = (e < 4) ? aR0[e & 3] : aR1[e & 3];
        const float az = (e < 4) ? aZ0[e & 3] : aZ1[e & 3];
        const float an = (e < 4) ? aN0[e & 3] : aN1[e & 3];
        const float r  = fast_rcp(1.0f + fast_exp2(ar));
        const float z  = fast_rcp(1.0f + fast_exp2(az));
        const float pn = fmaf(r, an, xb * wiN[e]);           // scaled 2log2e
        const float n  = fmaf(-2.0f, fast_rcp(fast_exp2(pn) + 1.0f), 1.0f);
        hs[nt][e] = fmaf(z, hs[nt][e] - n, n);               // n + z*(h-n)
      }
    }
    xv[0] = xn[0]; xv[1] = xn[1]; xv[2] = xn[2]; xv[3] = xn[3];
  }

  // ---- transpose h to per-thread rows via LDS (one-time) ----
  __shared__ float hsh[256][36];
#pragma unroll
  for (int nt = 0; nt < 4; ++nt) {
    const int row = wid * 64 + nt * 16 + c;
#pragma unroll
    for (int q = 0; q < 2; ++q) {
      floatx4 v = {hs[nt][q * 4 + 0], hs[nt][q * 4 + 1],
                   hs[nt][q * 4 + 2], hs[nt][q * 4 + 3]};
      *(floatx4*)&hsh[row][q * 16 + 4 * p] = v;
    }
  }
  __syncthreads();

  // ---- per-thread fp32 MLP head (phase-split, low VGPR) ----
  const int b = blockBase + threadIdx.x;
  const float s0 = weight_norm[b];
  const float s1 = grad_norm[b];
  const float s2 = loss_current[b];
  const float s3 = step_progress[b];

  float a1[M];
#pragma unroll
  for (int m = 0; m < M; ++m) a1[m] = b1[m];
#pragma unroll
  for (int m = 0; m < M; ++m) a1[m] = fmaf(s0, W1[0 * M + m], a1[m]);
#pragma unroll
  for (int m = 0; m < M; ++m) a1[m] = fmaf(s1, W1[1 * M + m], a1[m]);
#pragma unroll
  for (int m = 0; m < M; ++m) a1[m] = fmaf(s2, W1[2 * M + m], a1[m]);
#pragma unroll
  for (int m = 0; m < M; ++m) a1[m] = fmaf(s3, W1[3 * M + m], a1[m]);
#pragma unroll
  for (int k = 0; k < H; ++k) {
    const float hk = hsh[threadIdx.x][k];
#pragma unroll
    for (int m = 0; m < M; ++m)
      a1[m] = fmaf(hk, W1[(4 + k) * M + m], a1[m]);
  }
#pragma unroll
  for (int m = 0; m < M; ++m) a1[m] = fmaxf(a1[m], 0.0f);

  float logit = b3[0];
#pragma unroll
  for (int hf = 0; hf < 2; ++hf) {
    float a2[32];
#pragma unroll
    for (int m = 0; m < 32; ++m) a2[m] = b2[hf * 32 + m];
#pragma unroll
    for (int i = 0; i < M; ++i) {
      const float xi = a1[i];
#pragma unroll
      for (int m = 0; m < 32; ++m)
        a2[m] = fmaf(xi, W2[i * M + hf * 32 + m], a2[m]);
    }
#pragma unroll
    for (int m = 0; m < 32; ++m)
      logit = fmaf(fmaxf(a2[m], 0.0f), W3[hf * 32 + m], logit);
  }

  out[b] = fmaf(fast_sigmoid(logit), 100.0f - 1e-8f, 1e-8f);
}

}  // namespace

extern "C" void kernel_launch(void* const* d_in, const int* in_sizes, int n_in,
                              void* d_out, int out_size, void* d_ws, size_t ws_size,
                              hipStream_t stream) {
  const float* loss_history  = (const float*)d_in[0];
  const float* weight_norm   = (const float*)d_in[1];
  const float* grad_norm     = (const float*)d_in[2];
  const float* loss_current  = (const float*)d_in[3];
  const float* step_progress = (const float*)d_in[4];
  const float* Wi            = (const float*)d_in[5];
  const float* Wh            = (const float*)d_in[6];
  const float* bh            = (const float*)d_in[7];
  const float* W1            = (const float*)d_in[8];
  const float* b1            = (const float*)d_in[9];
  const float* W2            = (const float*)d_in[10];
  const float* b2            = (const float*)d_in[11];
  const float* W3            = (const float*)d_in[12];
  const float* b3            = (const float*)d_in[13];
  float* out = (float*)d_out;

  const int B = in_sizes[1];          // weight_norm is [B]; B % 256 == 0
  const int grid = B / 256;           // 1 block = 4 waves = 256 batch rows
  lrpred_kernel<<<grid, 256, 0, stream>>>(
      loss_history, weight_norm, grad_norm, loss_current, step_progress,
      Wi, Wh, bh, W1, b1, W2, b2, W3, b3, out, B);
}